// Round 8
// 541.686 us; speedup vs baseline: 1.0095x; 1.0095x over previous
//
#include <hip/hip_runtime.h>
#include <math.h>

// Problem constants (fixed by reference)
#define BATCH 2048
#define CH    32      // C
#define NN    144     // H*W = 12*12
#define KNN   9
#define PAD   36      // LDS row stride (floats): 16B-aligned, 2-way bank alias = free
#define TPB   192     // 3 waves; threads 0..143 active, one node each

// exact GELU: x * 0.5 * (1 + erf(x/sqrt(2)))  (jax.nn.gelu approximate=False)
__device__ __forceinline__ float gelu_exact(float x) {
    return 0.5f * x * (1.0f + erff(x * 0.70710678118654752440f));
}

// One batch element per workgroup; one thread per node.
// LDS ~21.9KB -> ~7 blocks/CU resident (R3 was 47.6KB -> ~2). No spills at ~80 VGPR.
__global__ __launch_bounds__(TPB) void gcn_main(
        const float* __restrict__ xin,   // (B, C, H, W)
        const float* __restrict__ pos,   // (1, C, H, W)
        const float* __restrict__ rel,   // (1, N, N)
        const float* __restrict__ W1,  const float* __restrict__ B1,   // g_fc1 32x32
        const float* __restrict__ WC,  const float* __restrict__ BC,   // g_conv 64x64
        const float* __restrict__ W2,  const float* __restrict__ B2,   // g_fc2 32x64
        const float* __restrict__ F1,  const float* __restrict__ FB1,  // f_fc1 32x32
        const float* __restrict__ F2,  const float* __restrict__ FB2,  // f_fc2 32x32
        float* __restrict__ out) {
    const int t = threadIdx.x;
    const int n = t;                 // node index (threads >= NN idle)
    const long bb = blockIdx.x;

    __shared__ __align__(16) float  s_xfT[NN * PAD];  // (n,c) g_fc1 output
    __shared__ float2 s_sr[NN];                       // (sq, rinv)

    const float* xb = xin + bb * (CH * NN) + n;   // column n (coalesced across lanes)
    const float* pb = pos + n;

    float xfn[CH];   // this node's xf row, lives in regs through the tail

    // ---- phase 1+2 fused: tmp col from global; xf = W1@tmp + B1 (W1 via s_load) ----
    if (t < NN) {
        float tc[CH];
        #pragma unroll
        for (int c = 0; c < CH; ++c) tc[c] = xb[c * NN] + pb[c * NN];
        float sum = 0.f;
        #pragma unroll
        for (int o = 0; o < CH; ++o) {
            float acc = B1[o];
            #pragma unroll
            for (int c = 0; c < CH; ++c) acc += W1[o * CH + c] * tc[c];
            xfn[o] = acc;
            sum += acc * acc;
        }
        float4* xr = (float4*)&s_xfT[n * PAD];
        #pragma unroll
        for (int q = 0; q < 8; ++q)
            xr[q] = make_float4(xfn[4*q], xfn[4*q+1], xfn[4*q+2], xfn[4*q+3]);
        float r = 1.0f / fmaxf(sqrtf(sum), 1e-12f);
        s_sr[n] = make_float2(sum * r * r, r);
    }
    __syncthreads();
    if (t >= NN) return;   // tail is per-thread, read-only LDS: no more barriers

    // ---- phase 4: k-NN over all m ----
    const float sqn = s_sr[n].x;
    const float rn2 = 2.0f * s_sr[n].y;
    float bestd[KNN];
    int   besti[KNN];
    #pragma unroll
    for (int k = 0; k < KNN; ++k) { bestd[k] = INFINITY; besti[k] = 0; }

    const float* reln = rel + n * NN;
    for (int mb = 0; mb < NN / 16; ++mb) {
        float rl[16];
        const float4* rp = (const float4*)(reln + mb * 16);
        #pragma unroll
        for (int q = 0; q < 4; ++q) {
            float4 v = rp[q];
            rl[4*q] = v.x; rl[4*q+1] = v.y; rl[4*q+2] = v.z; rl[4*q+3] = v.w;
        }
        #pragma unroll
        for (int mm = 0; mm < 16; ++mm) {
            const int m = mb * 16 + mm;
            const float4* row = (const float4*)&s_xfT[m * PAD];  // broadcast read
            float dot = 0.f;
            #pragma unroll
            for (int q = 0; q < 8; ++q) {
                float4 v = row[q];
                dot += xfn[4*q] * v.x + xfn[4*q+1] * v.y
                     + xfn[4*q+2] * v.z + xfn[4*q+3] * v.w;
            }
            float2 sr = s_sr[m];
            float d = (sqn + sr.x + rl[mm]) - rn2 * sr.y * dot;
            // strict < matches lax.top_k tie-break (lower index wins; m ascends)
            if (d < bestd[KNN - 1]) {
                bestd[KNN - 1] = d; besti[KNN - 1] = m;
                #pragma unroll
                for (int k = KNN - 1; k > 0; --k) {
                    if (bestd[k] < bestd[k - 1]) {
                        float td = bestd[k]; bestd[k] = bestd[k - 1]; bestd[k - 1] = td;
                        int   ti = besti[k]; besti[k] = besti[k - 1]; besti[k - 1] = ti;
                    }
                }
            }
        }
    }

    // ---- residual base: x2r = B2 + tmp (global re-read, L1-hot, coalesced) ----
    float x2r[CH];
    #pragma unroll
    for (int o = 0; o < CH; ++o) x2r[o] = B2[o] + xb[o * NN] + pb[o * NN];

    // ---- phase 5: max-relative (gathered rows) ----
    float mrel[CH];
    #pragma unroll
    for (int c = 0; c < CH; ++c) mrel[c] = -INFINITY;
    #pragma unroll
    for (int k = 0; k < KNN; ++k) {
        const float4* nr = (const float4*)&s_xfT[besti[k] * PAD];
        #pragma unroll
        for (int q = 0; q < 8; ++q) {
            float4 v = nr[q];
            mrel[4*q]   = fmaxf(mrel[4*q],   v.x);
            mrel[4*q+1] = fmaxf(mrel[4*q+1], v.y);
            mrel[4*q+2] = fmaxf(mrel[4*q+2], v.z);
            mrel[4*q+3] = fmaxf(mrel[4*q+3], v.w);
        }
    }
    #pragma unroll
    for (int c = 0; c < CH; ++c) mrel[c] -= xfn[c];

    // ---- phase 6: hc = gelu(WC@stacked + BC); x2r += W2@hc (streamed per j) ----
    // stacked[2c] = xfn[c], stacked[2c+1] = mrel[c]; WC/W2 rows wave-uniform -> s_load
    #pragma unroll 2
    for (int j = 0; j < 2 * CH; ++j) {
        float acc = BC[j];
        const float* wr = WC + j * 2 * CH;
        #pragma unroll
        for (int c = 0; c < CH; ++c)
            acc += wr[2*c] * xfn[c] + wr[2*c + 1] * mrel[c];
        float h = gelu_exact(acc);
        #pragma unroll
        for (int o = 0; o < CH; ++o) x2r[o] += W2[o * 2 * CH + j] * h;
    }

    // ---- phase 7: FFN + residual + store ----
    float yv[CH];
    #pragma unroll
    for (int o = 0; o < CH; ++o) {
        float acc = FB1[o];
        #pragma unroll
        for (int c = 0; c < CH; ++c) acc += F1[o * CH + c] * x2r[c];
        yv[o] = gelu_exact(acc);
    }
    float* ob = out + bb * (CH * NN) + n;
    #pragma unroll
    for (int o = 0; o < CH; ++o) {
        float acc = FB2[o];
        #pragma unroll
        for (int c = 0; c < CH; ++c) acc += F2[o * CH + c] * yv[c];
        ob[o * NN] = acc + x2r[o];
    }
}

extern "C" void kernel_launch(void* const* d_in, const int* in_sizes, int n_in,
                              void* d_out, int out_size, void* d_ws, size_t ws_size,
                              hipStream_t stream) {
    const float* xin = (const float*)d_in[0];
    const float* pos = (const float*)d_in[1];
    const float* rel = (const float*)d_in[2];
    const float* w1  = (const float*)d_in[3];
    const float* b1  = (const float*)d_in[4];
    const float* wc  = (const float*)d_in[5];
    const float* bc  = (const float*)d_in[6];
    const float* w2  = (const float*)d_in[7];
    const float* b2  = (const float*)d_in[8];
    const float* f1  = (const float*)d_in[9];
    const float* fb1 = (const float*)d_in[10];
    const float* f2  = (const float*)d_in[11];
    const float* fb2 = (const float*)d_in[12];
    float* out = (float*)d_out;

    dim3 grid(BATCH), blk(TPB);
    gcn_main<<<grid, blk, 0, stream>>>(xin, pos, rel,
                                       w1, b1, wc, bc, w2, b2,
                                       f1, fb1, f2, fb2, out);
}

// Round 9
// 458.797 us; speedup vs baseline: 1.1919x; 1.1807x over previous
//
#include <hip/hip_runtime.h>
#include <math.h>

// Problem constants (fixed by reference)
#define BATCH 2048
#define CH    32      // C
#define NN    144     // H*W = 12*12
#define KNN   9
#define PAD   36      // LDS row stride (floats): 16B-aligned, 2-way bank alias = free
#define TPB   192     // 3 waves
#define HCP   68      // tail-kernel pool row pitch (u32/f32)

typedef short s16x8 __attribute__((ext_vector_type(8)));   // 8 bf16 bit-patterns
typedef float f32x4 __attribute__((ext_vector_type(4)));

// exact GELU: x * 0.5 * (1 + erf(x/sqrt(2)))  (jax.nn.gelu approximate=False)
__device__ __forceinline__ float gelu_exact(float x) {
    return 0.5f * x * (1.0f + erff(x * 0.70710678118654752440f));
}

// ---------------- kernel A: K0 with runtime-dead tail branch ----------------
// Phases 1/4/5 are round-0 verbatim; phases 6/7 kept in-function (opaque
// run_tail arg) to minimize codegen perturbation of the front. run_tail=0:
// store (xfn, mrel) to ws and exit. run_tail=1: behave exactly like K0.
__global__ __launch_bounds__(TPB) void gcn_main(
        const float* __restrict__ xin,   // (B, C, H, W)
        const float* __restrict__ pos,   // (1, C, H, W)
        const float* __restrict__ rel,   // (1, N, N)
        const float* __restrict__ W1,  const float* __restrict__ B1,   // g_fc1 32x32
        const float* __restrict__ WC,  const float* __restrict__ BC,   // g_conv 64x64
        const float* __restrict__ W2,  const float* __restrict__ B2,   // g_fc2 32x64
        const float* __restrict__ F1,  const float* __restrict__ FB1,  // f_fc1 32x32
        const float* __restrict__ F2,  const float* __restrict__ FB2,  // f_fc2 32x32
        float* __restrict__ out,
        float* __restrict__ ws, const int run_tail) {
    const int t = threadIdx.x;
    const int n = t;                 // node index (threads >= NN idle)
    const long bb = blockIdx.x;

    __shared__ __align__(16) float  s_xfT[NN * PAD];  // (n,c) g_fc1 output
    __shared__ float2 s_sr[NN];                       // (sq, rinv)

    const float* xb = xin + bb * (CH * NN) + n;   // column n (coalesced across lanes)
    const float* pb = pos + n;

    float xfn[CH];   // this node's xf row, lives in regs through the tail

    // ---- phase 1+2 fused: tmp col from global; xf = W1@tmp + B1 (W1 via s_load) ----
    if (t < NN) {
        float tc[CH];
        #pragma unroll
        for (int c = 0; c < CH; ++c) tc[c] = xb[c * NN] + pb[c * NN];
        float sum = 0.f;
        #pragma unroll
        for (int o = 0; o < CH; ++o) {
            float acc = B1[o];
            #pragma unroll
            for (int c = 0; c < CH; ++c) acc += W1[o * CH + c] * tc[c];
            xfn[o] = acc;
            sum += acc * acc;
        }
        float4* xr = (float4*)&s_xfT[n * PAD];
        #pragma unroll
        for (int q = 0; q < 8; ++q)
            xr[q] = make_float4(xfn[4*q], xfn[4*q+1], xfn[4*q+2], xfn[4*q+3]);
        float r = 1.0f / fmaxf(sqrtf(sum), 1e-12f);
        s_sr[n] = make_float2(sum * r * r, r);
    }
    __syncthreads();
    if (t >= NN) return;   // tail is per-thread, read-only LDS: no more barriers

    // ---- phase 4: k-NN over all m ----
    const float sqn = s_sr[n].x;
    const float rn2 = 2.0f * s_sr[n].y;
    float bestd[KNN];
    int   besti[KNN];
    #pragma unroll
    for (int k = 0; k < KNN; ++k) { bestd[k] = INFINITY; besti[k] = 0; }

    const float* reln = rel + n * NN;
    for (int mb = 0; mb < NN / 16; ++mb) {
        float rl[16];
        const float4* rp = (const float4*)(reln + mb * 16);
        #pragma unroll
        for (int q = 0; q < 4; ++q) {
            float4 v = rp[q];
            rl[4*q] = v.x; rl[4*q+1] = v.y; rl[4*q+2] = v.z; rl[4*q+3] = v.w;
        }
        #pragma unroll
        for (int mm = 0; mm < 16; ++mm) {
            const int m = mb * 16 + mm;
            const float4* row = (const float4*)&s_xfT[m * PAD];  // broadcast read
            float dot = 0.f;
            #pragma unroll
            for (int q = 0; q < 8; ++q) {
                float4 v = row[q];
                dot += xfn[4*q] * v.x + xfn[4*q+1] * v.y
                     + xfn[4*q+2] * v.z + xfn[4*q+3] * v.w;
            }
            float2 sr = s_sr[m];
            float d = (sqn + sr.x + rl[mm]) - rn2 * sr.y * dot;
            // strict < matches lax.top_k tie-break (lower index wins; m ascends)
            if (d < bestd[KNN - 1]) {
                bestd[KNN - 1] = d; besti[KNN - 1] = m;
                #pragma unroll
                for (int k = KNN - 1; k > 0; --k) {
                    if (bestd[k] < bestd[k - 1]) {
                        float td = bestd[k]; bestd[k] = bestd[k - 1]; bestd[k - 1] = td;
                        int   ti = besti[k]; besti[k] = besti[k - 1]; besti[k - 1] = ti;
                    }
                }
            }
        }
    }

    // ---- residual base: x2r = B2 + tmp (global re-read, L1-hot, coalesced) ----
    float x2r[CH];
    #pragma unroll
    for (int o = 0; o < CH; ++o) x2r[o] = B2[o] + xb[o * NN] + pb[o * NN];

    // ---- phase 5: max-relative (gathered rows) ----
    float mrel[CH];
    #pragma unroll
    for (int c = 0; c < CH; ++c) mrel[c] = -INFINITY;
    #pragma unroll
    for (int k = 0; k < KNN; ++k) {
        const float4* nr = (const float4*)&s_xfT[besti[k] * PAD];
        #pragma unroll
        for (int q = 0; q < 8; ++q) {
            float4 v = nr[q];
            mrel[4*q]   = fmaxf(mrel[4*q],   v.x);
            mrel[4*q+1] = fmaxf(mrel[4*q+1], v.y);
            mrel[4*q+2] = fmaxf(mrel[4*q+2], v.z);
            mrel[4*q+3] = fmaxf(mrel[4*q+3], v.w);
        }
    }
    #pragma unroll
    for (int c = 0; c < CH; ++c) mrel[c] -= xfn[c];

    if (run_tail) {
        // ---- phase 6: hc = gelu(WC@stacked + BC); x2r += W2@hc (verbatim) ----
        #pragma unroll 2
        for (int j = 0; j < 2 * CH; ++j) {
            float acc = BC[j];
            const float* wr = WC + j * 2 * CH;
            #pragma unroll
            for (int c = 0; c < CH; ++c)
                acc += wr[2*c] * xfn[c] + wr[2*c + 1] * mrel[c];
            float h = gelu_exact(acc);
            #pragma unroll
            for (int o = 0; o < CH; ++o) x2r[o] += W2[o * 2 * CH + j] * h;
        }

        // ---- phase 7: FFN + residual + store (verbatim) ----
        float yv[CH];
        #pragma unroll
        for (int o = 0; o < CH; ++o) {
            float acc = FB1[o];
            #pragma unroll
            for (int c = 0; c < CH; ++c) acc += F1[o * CH + c] * x2r[c];
            yv[o] = gelu_exact(acc);
        }
        float* ob = out + bb * (CH * NN) + n;
        #pragma unroll
        for (int o = 0; o < CH; ++o) {
            float acc = FB2[o];
            #pragma unroll
            for (int c = 0; c < CH; ++c) acc += F2[o * CH + c] * yv[c];
            ob[o * NN] = acc + x2r[o];
        }
    } else {
        // store (xfn, mrel) for the tail kernel; coalesced across lanes
        float* wsb = ws + bb * (2 * CH * NN) + n;
        #pragma unroll
        for (int o = 0; o < CH; ++o) {
            wsb[o * NN]        = xfn[o];
            wsb[(CH + o) * NN] = mrel[o];
        }
    }
}

// ---------------- kernel B: MFMA tail (phases 6/7) with probes ----------------
// float -> bf16 (RNE) bit pattern; values finite
__device__ __forceinline__ unsigned bf_hi(float f) {
    unsigned u = __float_as_uint(f);
    return (u + 0x7fffu + ((u >> 16) & 1u)) >> 16;
}
__device__ __forceinline__ float bf_up(unsigned h) { return __uint_as_float(h << 16); }
__device__ __forceinline__ unsigned pack2(float f) {     // hi | lo<<16, 2-split
    unsigned h = bf_hi(f);
    unsigned l = bf_hi(f - bf_up(h));
    return h | (l << 16);
}
__device__ __forceinline__ float unpk(unsigned u) {      // hi+lo value
    return bf_up(u & 0xffffu) + bf_up(u >> 16);
}
__device__ __forceinline__ void unpack8(const unsigned* p, s16x8& hi, s16x8& lo) {
    const uint4* q = (const uint4*)p;
    uint4 u0 = q[0], u1 = q[1];
    unsigned w[8] = {u0.x, u0.y, u0.z, u0.w, u1.x, u1.y, u1.z, u1.w};
    short h[8], l[8];
    #pragma unroll
    for (int e = 0; e < 8; ++e) { h[e] = (short)(w[e] & 0xffffu); l[e] = (short)(w[e] >> 16); }
    hi = (s16x8){h[0], h[1], h[2], h[3], h[4], h[5], h[6], h[7]};
    lo = (s16x8){l[0], l[1], l[2], l[3], l[4], l[5], l[6], l[7]};
}
__device__ __forceinline__ void split8(const float* p, s16x8& hi, s16x8& lo) {
    const float4* q = (const float4*)p;
    float4 v0 = q[0], v1 = q[1];
    float f[8] = {v0.x, v0.y, v0.z, v0.w, v1.x, v1.y, v1.z, v1.w};
    short h[8], l[8];
    #pragma unroll
    for (int e = 0; e < 8; ++e) {
        unsigned a = bf_hi(f[e]);
        h[e] = (short)a;
        l[e] = (short)bf_hi(f[e] - bf_up(a));
    }
    hi = (s16x8){h[0], h[1], h[2], h[3], h[4], h[5], h[6], h[7]};
    lo = (s16x8){l[0], l[1], l[2], l[3], l[4], l[5], l[6], l[7]};
}
#define MFMA3(acc, ah, al, bh, bl)                                              \
    acc = __builtin_amdgcn_mfma_f32_16x16x32_bf16(ah, bh, acc, 0, 0, 0);        \
    acc = __builtin_amdgcn_mfma_f32_16x16x32_bf16(ah, bl, acc, 0, 0, 0);        \
    acc = __builtin_amdgcn_mfma_f32_16x16x32_bf16(al, bh, acc, 0, 0, 0);

__global__ __launch_bounds__(TPB) void gcn_tail(
        const float* __restrict__ xin, const float* __restrict__ pos,
        const float* __restrict__ WC,  const float* __restrict__ BC,
        const float* __restrict__ W2,  const float* __restrict__ B2,
        const float* __restrict__ F1,  const float* __restrict__ FB1,
        const float* __restrict__ F2,  const float* __restrict__ FB2,
        const float* __restrict__ ws,  float* __restrict__ out) {
    const int t = threadIdx.x;
    const int n = t;
    const long bb = blockIdx.x;

    __shared__ __align__(16) unsigned s_pool[NN * HCP];   // staged operands (39KB)
    __shared__ float s_x2[NN * 33];                       // x2r -> x2 (19KB)
    __shared__ int s_flag;

    float xfn[CH], mrel[CH], x2r[CH];
    if (t == 0) s_flag = 0;

    const float* wsb = ws + bb * (2 * CH * NN) + n;
    const float* xb  = xin + bb * (CH * NN) + n;
    const float* pb  = pos + n;

    // stage 0: load features, residual base; pack stacked row; x2r -> LDS
    if (t < NN) {
        #pragma unroll
        for (int o = 0; o < CH; ++o) {
            xfn[o]  = wsb[o * NN];
            mrel[o] = wsb[(CH + o) * NN];
            x2r[o]  = B2[o] + xb[o * NN] + pb[o * NN];
        }
        unsigned* sr = s_pool + n * HCP;
        #pragma unroll
        for (int e = 0; e < CH; ++e) {
            sr[2*e]     = pack2(xfn[e]);
            sr[2*e + 1] = pack2(mrel[e]);
        }
        #pragma unroll
        for (int o = 0; o < CH; ++o) s_x2[n * 33 + o] = x2r[o];
    }
    __syncthreads();

    const int wv   = t >> 6;
    const int lane = t & 63;
    const int lr   = lane & 15;
    const int lq   = lane >> 4;
    const int koff = lq * 8;

    // ---- stage 1: hc = gelu(stacked @ WC^T + BC), 144x64 ----
    f32x4 acc1[3][4];
    #pragma unroll
    for (int mt = 0; mt < 3; ++mt)
        #pragma unroll
        for (int nt = 0; nt < 4; ++nt) acc1[mt][nt] = (f32x4){0.f, 0.f, 0.f, 0.f};
    #pragma unroll
    for (int ks = 0; ks < 2; ++ks) {
        s16x8 bh[4], bl[4];
        #pragma unroll
        for (int nt = 0; nt < 4; ++nt)
            split8(&WC[(nt*16 + lr) * 64 + ks*32 + koff], bh[nt], bl[nt]);
        #pragma unroll
        for (int mt = 0; mt < 3; ++mt) {
            s16x8 ah, al;
            unpack8(s_pool + ((wv*3 + mt)*16 + lr) * HCP + ks*32 + koff, ah, al);
            #pragma unroll
            for (int nt = 0; nt < 4; ++nt) { MFMA3(acc1[mt][nt], ah, al, bh[nt], bl[nt]); }
        }
    }
    __syncthreads();   // all stacked reads done
    // write hc packed in-place (C/D layout m89: col=lane&15, row=4*(lane>>4)+r)
    #pragma unroll
    for (int mt = 0; mt < 3; ++mt)
        #pragma unroll
        for (int nt = 0; nt < 4; ++nt)
            #pragma unroll
            for (int r = 0; r < 4; ++r) {
                const int row = (wv*3 + mt)*16 + 4*lq + r;
                const int col = nt*16 + lr;
                s_pool[row * HCP + col] = pack2(gelu_exact(acc1[mt][nt][r] + BC[col]));
            }
    __syncthreads();
    // probe hc (scalar oracle from registers)
    if (t < NN) {
        const int jp = n & 63;
        float a = BC[jp];
        const float* wr = WC + jp * 2 * CH;
        #pragma unroll
        for (int c = 0; c < CH; ++c) a += wr[2*c] * xfn[c] + wr[2*c + 1] * mrel[c];
        if (fabsf(gelu_exact(a) - unpk(s_pool[n * HCP + jp])) > 0.05f) s_flag = 1;
    }
    __syncthreads();

    // ---- stage 2: x2 = x2r + hc @ W2^T, 144x32 ----
    f32x4 acc2[3][2];
    #pragma unroll
    for (int mt = 0; mt < 3; ++mt)
        #pragma unroll
        for (int nt = 0; nt < 2; ++nt) acc2[mt][nt] = (f32x4){0.f, 0.f, 0.f, 0.f};
    #pragma unroll
    for (int ks = 0; ks < 2; ++ks) {
        s16x8 bh[2], bl[2];
        #pragma unroll
        for (int nt = 0; nt < 2; ++nt)
            split8(&W2[(nt*16 + lr) * 64 + ks*32 + koff], bh[nt], bl[nt]);
        #pragma unroll
        for (int mt = 0; mt < 3; ++mt) {
            s16x8 ah, al;
            unpack8(s_pool + ((wv*3 + mt)*16 + lr) * HCP + ks*32 + koff, ah, al);
            #pragma unroll
            for (int nt = 0; nt < 2; ++nt) { MFMA3(acc2[mt][nt], ah, al, bh[nt], bl[nt]); }
        }
    }
    float x2f[3][2][4];
    #pragma unroll
    for (int mt = 0; mt < 3; ++mt)
        #pragma unroll
        for (int nt = 0; nt < 2; ++nt)
            #pragma unroll
            for (int r = 0; r < 4; ++r) {
                const int row = (wv*3 + mt)*16 + 4*lq + r;
                const int col = nt*16 + lr;
                const float v = acc2[mt][nt][r] + s_x2[row * 33 + col];
                x2f[mt][nt][r] = v;
                s_x2[row * 33 + col] = v;          // element owned by this lane
            }
    __syncthreads();
    // probe x2 (hc still intact in pool)
    if (t < NN) {
        const int op = n & 31;
        float e = x2r[op];
        #pragma unroll
        for (int j = 0; j < 2 * CH; ++j) e += W2[op * 2 * CH + j] * unpk(s_pool[n * HCP + j]);
        if (fabsf(e - s_x2[n * 33 + op]) > 0.1f) s_flag = 1;
    }
    __syncthreads();
    // write x2 packed into pool cols 0..31
    #pragma unroll
    for (int mt = 0; mt < 3; ++mt)
        #pragma unroll
        for (int nt = 0; nt < 2; ++nt)
            #pragma unroll
            for (int r = 0; r < 4; ++r)
                s_pool[((wv*3 + mt)*16 + 4*lq + r) * HCP + nt*16 + lr] = pack2(x2f[mt][nt][r]);
    __syncthreads();

    // ---- stage 3: y1 = gelu(x2 @ F1^T + FB1), K=32 ----
    f32x4 acc3[3][2];
    #pragma unroll
    for (int mt = 0; mt < 3; ++mt)
        #pragma unroll
        for (int nt = 0; nt < 2; ++nt) acc3[mt][nt] = (f32x4){0.f, 0.f, 0.f, 0.f};
    {
        s16x8 bh[2], bl[2];
        #pragma unroll
        for (int nt = 0; nt < 2; ++nt)
            split8(&F1[(nt*16 + lr) * 32 + koff], bh[nt], bl[nt]);
        #pragma unroll
        for (int mt = 0; mt < 3; ++mt) {
            s16x8 ah, al;
            unpack8(s_pool + ((wv*3 + mt)*16 + lr) * HCP + koff, ah, al);
            #pragma unroll
            for (int nt = 0; nt < 2; ++nt) { MFMA3(acc3[mt][nt], ah, al, bh[nt], bl[nt]); }
        }
    }
    // write y1 packed to cols 32..63 (disjoint from x2pack reads; no WAR)
    #pragma unroll
    for (int mt = 0; mt < 3; ++mt)
        #pragma unroll
        for (int nt = 0; nt < 2; ++nt)
            #pragma unroll
            for (int r = 0; r < 4; ++r) {
                const int row = (wv*3 + mt)*16 + 4*lq + r;
                const int col = nt*16 + lr;
                s_pool[row * HCP + 32 + col] = pack2(gelu_exact(acc3[mt][nt][r] + FB1[col]));
            }
    __syncthreads();
    // probe y1 (x2pack cols 0..31 intact)
    if (t < NN) {
        const int op = n & 31;
        float e = FB1[op];
        #pragma unroll
        for (int c = 0; c < CH; ++c) e += F1[op * CH + c] * unpk(s_pool[n * HCP + c]);
        if (fabsf(gelu_exact(e) - unpk(s_pool[n * HCP + 32 + op])) > 0.1f) s_flag = 1;
    }

    // ---- stage 4: y = x2 + y1 @ F2^T + FB2 (reads only; safe with probe) ----
    f32x4 acc4[3][2];
    #pragma unroll
    for (int mt = 0; mt < 3; ++mt)
        #pragma unroll
        for (int nt = 0; nt < 2; ++nt) acc4[mt][nt] = (f32x4){0.f, 0.f, 0.f, 0.f};
    {
        s16x8 bh[2], bl[2];
        #pragma unroll
        for (int nt = 0; nt < 2; ++nt)
            split8(&F2[(nt*16 + lr) * 32 + koff], bh[nt], bl[nt]);
        #pragma unroll
        for (int mt = 0; mt < 3; ++mt) {
            s16x8 ah, al;
            unpack8(s_pool + ((wv*3 + mt)*16 + lr) * HCP + 32 + koff, ah, al);
            #pragma unroll
            for (int nt = 0; nt < 2; ++nt) { MFMA3(acc4[mt][nt], ah, al, bh[nt], bl[nt]); }
        }
    }
    __syncthreads();   // all pool reads (stage-4 A, y1 probe) done
    float* poolf = (float*)s_pool;
    #pragma unroll
    for (int mt = 0; mt < 3; ++mt)
        #pragma unroll
        for (int nt = 0; nt < 2; ++nt)
            #pragma unroll
            for (int r = 0; r < 4; ++r) {
                const int row = (wv*3 + mt)*16 + 4*lq + r;
                const int col = nt*16 + lr;
                poolf[row * HCP + col] = acc4[mt][nt][r] + FB2[col] + s_x2[row * 33 + col];
            }
    __syncthreads();

    if (t >= NN) return;
    if (s_flag != 0) {
        // scalar fallback: verbatim phases 6/7 from registers (tolerance-safe)
        #pragma unroll 2
        for (int j = 0; j < 2 * CH; ++j) {
            float acc = BC[j];
            const float* wr = WC + j * 2 * CH;
            #pragma unroll
            for (int c = 0; c < CH; ++c)
                acc += wr[2*c] * xfn[c] + wr[2*c + 1] * mrel[c];
            float h = gelu_exact(acc);
            #pragma unroll
            for (int o = 0; o < CH; ++o) x2r[o] += W2[o * 2 * CH + j] * h;
        }
        float yv[CH];
        #pragma unroll
        for (int o = 0; o < CH; ++o) {
            float acc = FB1[o];
            #pragma unroll
            for (int c = 0; c < CH; ++c) acc += F1[o * CH + c] * x2r[c];
            yv[o] = gelu_exact(acc);
        }
        float* ob = out + bb * (CH * NN) + n;
        #pragma unroll
        for (int o = 0; o < CH; ++o) {
            float acc = FB2[o];
            #pragma unroll
            for (int c = 0; c < CH; ++c) acc += F2[o * CH + c] * yv[c];
            ob[o * NN] = acc + x2r[o];
        }
        return;
    }
    // coalesced store (same pattern as K0)
    float* ob = out + bb * (CH * NN) + n;
    #pragma unroll
    for (int o = 0; o < CH; ++o) ob[o * NN] = poolf[n * HCP + o];
}

extern "C" void kernel_launch(void* const* d_in, const int* in_sizes, int n_in,
                              void* d_out, int out_size, void* d_ws, size_t ws_size,
                              hipStream_t stream) {
    const float* xin = (const float*)d_in[0];
    const float* pos = (const float*)d_in[1];
    const float* rel = (const float*)d_in[2];
    const float* w1  = (const float*)d_in[3];
    const float* b1  = (const float*)d_in[4];
    const float* wc  = (const float*)d_in[5];
    const float* bc  = (const float*)d_in[6];
    const float* w2  = (const float*)d_in[7];
    const float* b2  = (const float*)d_in[8];
    const float* f1  = (const float*)d_in[9];
    const float* fb1 = (const float*)d_in[10];
    const float* f2  = (const float*)d_in[11];
    const float* fb2 = (const float*)d_in[12];
    float* out = (float*)d_out;

    const size_t need = (size_t)BATCH * (2 * CH) * NN * sizeof(float);  // 75.5 MB
    const int run_tail = (d_ws == nullptr || ws_size < need) ? 1 : 0;

    dim3 grid(BATCH), blk(TPB);
    gcn_main<<<grid, blk, 0, stream>>>(xin, pos, rel,
                                       w1, b1, wc, bc, w2, b2,
                                       f1, fb1, f2, fb2, out,
                                       (float*)d_ws, run_tail);
    if (!run_tail) {
        gcn_tail<<<grid, blk, 0, stream>>>(xin, pos,
                                           wc, bc, w2, b2,
                                           f1, fb1, f2, fb2,
                                           (const float*)d_ws, out);
    }
}